// Round 7
// baseline (180.701 us; speedup 1.0000x reference)
//
#include <hip/hip_runtime.h>
#include <cstdint>
#include <cstddef>

using bf16 = __bf16;
typedef float f32x16 __attribute__((ext_vector_type(16)));
typedef __bf16 bf16x8v __attribute__((ext_vector_type(8)));
typedef __bf16 bf16x4v __attribute__((ext_vector_type(4)));

// Problem constants: B=4, S=2048, D=1024
#define NX   8388608      // 4*2048*1024
#define NW   1048576      // 1024*1024
#define SB   2048
#define DD   1024

__device__ __forceinline__ void gload_lds16(const bf16* g, bf16* l) {
    __builtin_amdgcn_global_load_lds(
        (const __attribute__((address_space(1))) void*)(g),
        (__attribute__((address_space(3))) void*)(l), 16, 0, 0);
}

// ---------------------------------------------------------------------------
// Convert fp32 inputs -> bf16 in workspace; copy biases (fp32) contiguous.
// ---------------------------------------------------------------------------
__global__ __launch_bounds__(256)
void convert_kernel(const float* __restrict__ x1,
                    const float* __restrict__ Wq, const float* __restrict__ Wk,
                    const float* __restrict__ Wv,
                    const float* __restrict__ bq, const float* __restrict__ bk,
                    const float* __restrict__ bv,
                    bf16* __restrict__ xb, bf16* __restrict__ wb,
                    float* __restrict__ biases)
{
    const int NX4 = NX / 4;
    const int NW4 = NW / 4;
    const int NMAT = NX4 + 3 * NW4;
    const int total = NMAT + 768;
    for (int i = blockIdx.x * 256 + threadIdx.x; i < total; i += gridDim.x * 256) {
        if (i < NMAT) {
            const float* src; bf16* dst; int j;
            if (i < NX4) { src = x1; dst = xb; j = i; }
            else {
                int w = (i - NX4) / NW4;
                j = (i - NX4) - w * NW4;
                src = (w == 0) ? Wq : (w == 1) ? Wk : Wv;
                dst = wb + (size_t)w * NW;
            }
            float4 f = ((const float4*)src)[j];
            bf16x4v o;
            o[0] = (bf16)f.x; o[1] = (bf16)f.y; o[2] = (bf16)f.z; o[3] = (bf16)f.w;
            ((bf16x4v*)dst)[j] = o;
        } else {
            int j = i - NMAT;
            const float* src = (j < 256) ? bq : (j < 512) ? bk : bv;
            ((float4*)biases)[j] = ((const float4*)src)[j & 255];
        }
    }
}

// ---------------------------------------------------------------------------
// 2-phase 128x128 GEMM, mfma_f32_32x32x16_bf16 (half the MFMA instructions
// of the 16x16x32 version for the same FLOPs; m119: 2495 vs 2176 TF ubench).
// C[m][n] = scale * sum_k A[m][k]*B[n][k] (+ epilogue routing)
// A: M x K row-major bf16, B: N x K row-major bf16 (both K-contiguous).
// 4 waves (2x2 of 64x64; each wave 2x2 frags of 32x32).
// A/B frag: lane supplies row = lane&31, k = ks*16 + (lane>>5)*8 + j.
// C/D frag: col = lane&31, row = (reg&3) + 8*(reg>>2) + 4*(lane>>5)  [m101].
// LDS XOR-swizzle (chunk ^= row&7) via pre-swizzled global source; linear
// LDS dest for global_load_lds; conflict-free (rounds 1/3/5: 0 conflicts).
// T1 XCD-aware bijective block swizzle (nwg % 8 == 0).
// V=0: fused QKV epilogue (bias; col<1024 -> q, <2048 -> k, else v written
//      transposed [b][d][s]).
// V=1: scores: write P~ = exp2(acc*scale*log2e - 6*log2e) bf16 + partial
//      row-sums pRow[row*32 + bx*2 + wc] (deterministic, no atomics).
// V=2: PV: f32 out scaled by 1/rowsum (reduced from pRow at block entry).
// ---------------------------------------------------------------------------
template<int V, typename OutT>
__global__ __launch_bounds__(256)
void gemm_bt(const bf16* __restrict__ A, const bf16* __restrict__ B,
             OutT* __restrict__ C, bf16* __restrict__ vT,
             const float* __restrict__ bias, float* __restrict__ pRow,
             int N, int K,
             long sAz, long sBz, long sCz, float scale)
{
    __shared__ bf16 lA[128 * 64];
    __shared__ bf16 lB[128 * 64];
    __shared__ float inv[128];   // V==2 only
    const int z = blockIdx.z;
    A += (size_t)z * sAz;
    B += (size_t)z * sBz;
    C += (size_t)z * sCz;
    if constexpr (V == 1 || V == 2) pRow += (size_t)z * (SB * 32);

    // T1: XCD-aware bijective swizzle of the flattened 2D grid
    const int gx = gridDim.x;
    const int nwg = gx * gridDim.y;
    const int orig = (int)blockIdx.y * gx + (int)blockIdx.x;
    const int q8 = nwg >> 3;
    const int tile = (orig & 7) * q8 + (orig >> 3);
    const int bx = tile % gx;
    const int by = tile / gx;

    const int n0 = bx * 128;
    const int m0 = by * 128;
    const int t = threadIdx.x;
    const int lane = t & 63;
    const int wid = t >> 6;
    const int wr = wid >> 1, wc = wid & 1;

    if constexpr (V == 2) {
        // reduce 32 partial row-sums per row -> inv[] in LDS
        if (t < 128) {
            const float4* pr = (const float4*)&pRow[(size_t)(m0 + t) * 32];
            float s = 0.f;
            #pragma unroll
            for (int j = 0; j < 8; ++j) {
                float4 f = pr[j];
                s += f.x + f.y + f.z + f.w;
            }
            inv[t] = 1.0f / s;
        }
        __syncthreads();
    }

    f32x16 acc[2][2];
    #pragma unroll
    for (int m = 0; m < 2; ++m)
        #pragma unroll
        for (int n = 0; n < 2; ++n)
            #pragma unroll
            for (int r = 0; r < 16; ++r) acc[m][n][r] = 0.f;

    const int l31 = lane & 31;
    const int l5  = lane >> 5;

    for (int k0 = 0; k0 < K; k0 += 64) {
        #pragma unroll
        for (int l = 0; l < 4; ++l) {
            const int idx = l * 256 + t;
            const int row = idx >> 3;
            const int c   = idx & 7;
            const int gc  = c ^ (row & 7);   // inverse-swizzled source chunk
            gload_lds16(A + (size_t)(m0 + row) * K + k0 + gc * 8, &lA[idx * 8]);
            gload_lds16(B + (size_t)(n0 + row) * K + k0 + gc * 8, &lB[idx * 8]);
        }
        __syncthreads();
        #pragma unroll
        for (int ks = 0; ks < 4; ++ks) {
            bf16x8v af[2], bfr[2];
            #pragma unroll
            for (int m = 0; m < 2; ++m) {
                const int row = wr * 64 + m * 32 + l31;
                const int ch  = (ks * 2 + l5) ^ (row & 7);
                af[m] = *(const bf16x8v*)&lA[row * 64 + ch * 8];
            }
            #pragma unroll
            for (int n = 0; n < 2; ++n) {
                const int row = wc * 64 + n * 32 + l31;
                const int ch  = (ks * 2 + l5) ^ (row & 7);
                bfr[n] = *(const bf16x8v*)&lB[row * 64 + ch * 8];
            }
            #pragma unroll
            for (int m = 0; m < 2; ++m)
                #pragma unroll
                for (int n = 0; n < 2; ++n)
                    acc[m][n] = __builtin_amdgcn_mfma_f32_32x32x16_bf16(
                        af[m], bfr[n], acc[m][n], 0, 0, 0);
        }
        __syncthreads();
    }

    // epilogue: C/D map col=lane&31, row=(reg&3)+8*(reg>>2)+4*(lane>>5)
    const int hh = l5 << 2;

    if constexpr (V == 1) {
        const float sc2 = scale * 1.4426950408889634f;
        const float sh2 = -8.656170245333781f;   // -6 * log2(e)
        float rs[2][16];
        #pragma unroll
        for (int m = 0; m < 2; ++m)
            #pragma unroll
            for (int r = 0; r < 16; ++r) rs[m][r] = 0.f;

        #pragma unroll
        for (int m = 0; m < 2; ++m) {
            #pragma unroll
            for (int n = 0; n < 2; ++n) {
                const int col = n0 + wc * 64 + n * 32 + l31;
                #pragma unroll
                for (int r = 0; r < 16; ++r) {
                    const int lrow = wr * 64 + m * 32 + (r & 3) + ((r >> 2) << 3) + hh;
                    const float e = exp2f(fmaf(acc[m][n][r], sc2, sh2));
                    rs[m][r] += e;
                    C[(size_t)(m0 + lrow) * N + col] = (OutT)e;
                }
            }
        }
        // reduce across the 32 col-lanes of each half-wave
        #pragma unroll
        for (int m = 0; m < 2; ++m)
            #pragma unroll
            for (int r = 0; r < 16; ++r) {
                #pragma unroll
                for (int msk = 1; msk < 32; msk <<= 1)
                    rs[m][r] += __shfl_xor(rs[m][r], msk);
            }
        if (l31 == 0) {
            const int slot = bx * 2 + wc;
            #pragma unroll
            for (int m = 0; m < 2; ++m)
                #pragma unroll
                for (int r = 0; r < 16; ++r) {
                    const int lrow = wr * 64 + m * 32 + (r & 3) + ((r >> 2) << 3) + hh;
                    pRow[(size_t)(m0 + lrow) * 32 + slot] = rs[m][r];
                }
        }
    } else if constexpr (V == 2) {
        #pragma unroll
        for (int m = 0; m < 2; ++m) {
            #pragma unroll
            for (int n = 0; n < 2; ++n) {
                const int col = n0 + wc * 64 + n * 32 + l31;
                #pragma unroll
                for (int r = 0; r < 16; ++r) {
                    const int lrow = wr * 64 + m * 32 + (r & 3) + ((r >> 2) << 3) + hh;
                    C[(size_t)(m0 + lrow) * N + col] = (OutT)(acc[m][n][r] * inv[lrow]);
                }
            }
        }
    } else {  // V == 0: QKV routing
        #pragma unroll
        for (int m = 0; m < 2; ++m) {
            #pragma unroll
            for (int n = 0; n < 2; ++n) {
                const int col = n0 + wc * 64 + n * 32 + l31;
                const float bb = bias[col];
                if (col < 1024) {
                    #pragma unroll
                    for (int r = 0; r < 16; ++r) {
                        const int lrow = wr * 64 + m * 32 + (r & 3) + ((r >> 2) << 3) + hh;
                        C[(size_t)(m0 + lrow) * 1024 + col] = (OutT)(acc[m][n][r] + bb);
                    }
                } else if (col < 2048) {
                    #pragma unroll
                    for (int r = 0; r < 16; ++r) {
                        const int lrow = wr * 64 + m * 32 + (r & 3) + ((r >> 2) << 3) + hh;
                        C[NX + (size_t)(m0 + lrow) * 1024 + (col - 1024)] = (OutT)(acc[m][n][r] + bb);
                    }
                } else {
                    const int d = col - 2048;
                    #pragma unroll
                    for (int q = 0; q < 4; ++q) {
                        bf16x4v pk;
                        #pragma unroll
                        for (int j = 0; j < 4; ++j) pk[j] = (bf16)(acc[m][n][q * 4 + j] + bb);
                        const int srow = m0 + wr * 64 + m * 32 + (q << 3) + hh;
                        const int batch = srow >> 11, s = srow & 2047;
                        *(bf16x4v*)&vT[((size_t)batch << 21) + ((size_t)d << 11) + s] = pk;
                    }
                }
            }
        }
    }
}

// ---------------------------------------------------------------------------
extern "C" void kernel_launch(void* const* d_in, const int* in_sizes, int n_in,
                              void* d_out, int out_size, void* d_ws, size_t ws_size,
                              hipStream_t stream)
{
    const float* x1 = (const float*)d_in[0];
    const float* Wq = (const float*)d_in[1];
    const float* bq = (const float*)d_in[2];
    const float* Wk = (const float*)d_in[3];
    const float* bk = (const float*)d_in[4];
    const float* Wv = (const float*)d_in[5];
    const float* bv = (const float*)d_in[6];
    float* out = (float*)d_out;

    // workspace layout (bf16 elements unless noted)
    bf16* xb     = (bf16*)d_ws;             // x bf16; reused as pRow after QKV
    bf16* wb     = xb + NX;                 // 3*1048576 (Wq,Wk,Wv rows x 1024)
    bf16* qkb    = wb + 3 * NW;             // 2*8388608 (q then k)
    bf16* vTb    = qkb + 2 * (size_t)NX;    // 8388608 (V^T per batch [D][S])
    bf16* scores = vTb + NX;                // 4*2048*2048 (P~)
    float* biases = (float*)(scores + 4 * (size_t)SB * SB); // 3072 f32
    float* partial = (float*)xb;            // [4][2048][32] f32 (xb dead post-QKV)

    // 1. convert inputs to bf16
    convert_kernel<<<dim3(2048), dim3(256), 0, stream>>>(
        x1, Wq, Wk, Wv, bq, bk, bv, xb, wb, biases);

    // 2. fused QKV projection: M=8192, N=3072 (q|k|vT), K=1024
    gemm_bt<0, bf16><<<dim3(24, 64, 1), dim3(256), 0, stream>>>(
        xb, wb, qkb, vTb, biases, nullptr, 1024, 1024, 0L, 0L, 0L, 1.0f);

    // 3. P~ = exp(QK^T/32 - 6) per batch + partial row sums: M=N=2048, K=1024
    gemm_bt<1, bf16><<<dim3(16, 16, 4), dim3(256), 0, stream>>>(
        qkb, qkb + NX, scores, nullptr, nullptr, partial, SB, DD,
        (long)(SB * DD), (long)(SB * DD), (long)(SB * SB), 1.0f / 32.0f);

    // 4. out = (P~ V) / rowsum per batch: M=2048, N=1024, K=2048, f32 out
    gemm_bt<2, float><<<dim3(8, 16, 4), dim3(256), 0, stream>>>(
        scores, vTb, out, nullptr, nullptr, partial, DD, SB,
        (long)(SB * SB), (long)(SB * DD), (long)(SB * DD), 1.0f);
}

// Round 8
// 177.762 us; speedup vs baseline: 1.0165x; 1.0165x over previous
//
#include <hip/hip_runtime.h>
#include <cstdint>
#include <cstddef>

using bf16 = __bf16;
typedef float f32x4 __attribute__((ext_vector_type(4)));
typedef __bf16 bf16x8v __attribute__((ext_vector_type(8)));
typedef __bf16 bf16x4v __attribute__((ext_vector_type(4)));

// Problem constants: B=4, S=2048, D=1024
#define NX   8388608      // 4*2048*1024
#define NW   1048576      // 1024*1024
#define SB   2048
#define DD   1024

#define VMCNT(n) asm volatile("s_waitcnt vmcnt(" #n ")" ::: "memory")

__device__ __forceinline__ void gload_lds16(const bf16* g, bf16* l) {
    __builtin_amdgcn_global_load_lds(
        (const __attribute__((address_space(1))) void*)(g),
        (__attribute__((address_space(3))) void*)(l), 16, 0, 0);
}

// ---------------------------------------------------------------------------
// Convert fp32 inputs -> bf16 in workspace; copy biases (fp32) contiguous.
// ---------------------------------------------------------------------------
__global__ __launch_bounds__(256)
void convert_kernel(const float* __restrict__ x1,
                    const float* __restrict__ Wq, const float* __restrict__ Wk,
                    const float* __restrict__ Wv,
                    const float* __restrict__ bq, const float* __restrict__ bk,
                    const float* __restrict__ bv,
                    bf16* __restrict__ xb, bf16* __restrict__ wb,
                    float* __restrict__ biases)
{
    const int NX4 = NX / 4;
    const int NW4 = NW / 4;
    const int NMAT = NX4 + 3 * NW4;
    const int total = NMAT + 768;
    for (int i = blockIdx.x * 256 + threadIdx.x; i < total; i += gridDim.x * 256) {
        if (i < NMAT) {
            const float* src; bf16* dst; int j;
            if (i < NX4) { src = x1; dst = xb; j = i; }
            else {
                int w = (i - NX4) / NW4;
                j = (i - NX4) - w * NW4;
                src = (w == 0) ? Wq : (w == 1) ? Wk : Wv;
                dst = wb + (size_t)w * NW;
            }
            float4 f = ((const float4*)src)[j];
            bf16x4v o;
            o[0] = (bf16)f.x; o[1] = (bf16)f.y; o[2] = (bf16)f.z; o[3] = (bf16)f.w;
            ((bf16x4v*)dst)[j] = o;
        } else {
            int j = i - NMAT;
            const float* src = (j < 256) ? bq : (j < 512) ? bk : bv;
            ((float4*)biases)[j] = ((const float4*)src)[j & 255];
        }
    }
}

// ---------------------------------------------------------------------------
// 8-phase 256x256 GEMM (m201-geometry port), BK=64, 8 waves (2Mx4N), 512 thr.
// INTERLEAVED wave tiling: wave (wr,wc) owns rows m*32+wr*16, cols n*64+wc*16
// => phase (mq,nq) reads exactly A-half mq x B-half nq for ALL waves.
// Per tile: 4 phases {(0,0),(1,0),(0,1),(1,1)}; B-frags kept across mq-pair.
// Stage slots: p1: t+1.A1, p2: t+1.B1, p3: t+2.B0, p4: t+2.A0 (each region's
// last ds_read retires >=1 barrier before its stage issues - ledger-checked).
// One counted vmcnt(4) per tile at p4 => next tile fully resident (all waves
// issue stages in identical slot order, so per-wave vmcnt + barrier = global).
// LDS halves [128][64] bf16, chunk16 c holds global chunk c^(row&7) via
// pre-swizzled global source (linear dest); reads use the same XOR -> 0-conflict
// pattern (validated rounds 1/3/5).
// V=0: fused QKV epilogue (bias; col<1024 q, <2048 k, else vT [b][d][s]).
// V=1: P~ = exp(acc*scale - 6) bf16 + partial row-sums pRow[row*32+bx*4+wc].
// ---------------------------------------------------------------------------
template<int V, typename OutT>
__global__ __launch_bounds__(512)
void gemm8(const bf16* __restrict__ A, const bf16* __restrict__ B,
           OutT* __restrict__ C, bf16* __restrict__ vT,
           const float* __restrict__ bias, float* __restrict__ pRow,
           int N, int K, int NXT, long sA, long sB, long sC, float scale)
{
    __shared__ bf16 shA[2][2][8192];   // [buf][half][128*64] = 64 KiB
    __shared__ bf16 shB[2][2][8192];   // 64 KiB
    const int z = blockIdx.z;
    A += (size_t)z * sA; B += (size_t)z * sB; C += (size_t)z * sC;
    if constexpr (V == 1) pRow += (size_t)z * (SB * 32);

    // T1 XCD-aware bijective swizzle (gridDim.x % 8 == 0)
    const int nwg = gridDim.x;
    const int q8 = nwg >> 3;
    const int tile = ((int)blockIdx.x & 7) * q8 + ((int)blockIdx.x >> 3);
    const int bx = tile % NXT, by = tile / NXT;
    const int n0 = bx * 256, m0 = by * 256;

    const int tid = threadIdx.x;
    const int lane = tid & 63, wid = tid >> 6;
    const int wr = wid >> 2, wc = wid & 3;
    const int rl = lane & 15, lg = lane >> 4;
    const int wr16 = wr * 16, wc16 = wc * 16;

    const bf16* Ag = A + (size_t)m0 * K;
    const bf16* Bg = B + (size_t)n0 * K;

    auto stg = [&](const bf16* g, bf16* l) {   // one 128x64 half-tile
        #pragma unroll
        for (int j = 0; j < 2; ++j) {
            const int idx = j * 512 + tid;
            const int row = idx >> 3;
            const int c = idx & 7;
            gload_lds16(g + (size_t)row * K + ((c ^ (row & 7)) << 3), l + idx * 8);
        }
    };

    f32x4 acc[8][4];
    #pragma unroll
    for (int m = 0; m < 8; ++m)
        #pragma unroll
        for (int n = 0; n < 4; ++n) acc[m][n] = (f32x4){0.f, 0.f, 0.f, 0.f};

    const int NT = K >> 6;

    // prologue: t0 all 4 halves + t1.{A0,B0}; wait t0 resident (2 halves out)
    stg(Ag, &shA[0][0][0]);
    stg(Bg, &shB[0][0][0]);
    stg(Ag + (size_t)128 * K, &shA[0][1][0]);
    stg(Bg + (size_t)128 * K, &shB[0][1][0]);
    stg(Ag + 64, &shA[1][0][0]);
    stg(Bg + 64, &shB[1][0][0]);
    VMCNT(4);
    __builtin_amdgcn_s_barrier();

    bf16x8v af[4][2], bfr[2][2];

#define RD_A(mq)                                                               \
    {                                                                          \
        const bf16* ap = &shA[buf][mq][0];                                     \
        _Pragma("unroll") for (int i = 0; i < 4; ++i)                          \
            _Pragma("unroll") for (int kk = 0; kk < 2; ++kk) {                 \
                const int r = i * 32 + wr16 + rl;                              \
                af[i][kk] = *(const bf16x8v*)&ap[r * 64 +                      \
                    (((kk * 4 + lg) ^ (r & 7)) << 3)];                         \
            }                                                                  \
    }
#define RD_B(nq)                                                               \
    {                                                                          \
        const bf16* bp = &shB[buf][nq][0];                                     \
        _Pragma("unroll") for (int n = 0; n < 2; ++n)                          \
            _Pragma("unroll") for (int kk = 0; kk < 2; ++kk) {                 \
                const int r = n * 64 + wc16 + rl;                              \
                bfr[n][kk] = *(const bf16x8v*)&bp[r * 64 +                     \
                    (((kk * 4 + lg) ^ (r & 7)) << 3)];                         \
            }                                                                  \
    }
#define MM(mq, nq)                                                             \
    __builtin_amdgcn_s_barrier();                                              \
    asm volatile("s_waitcnt lgkmcnt(0)" ::: "memory");                         \
    __builtin_amdgcn_sched_barrier(0);                                         \
    __builtin_amdgcn_s_setprio(1);                                             \
    _Pragma("unroll") for (int i = 0; i < 4; ++i)                              \
        _Pragma("unroll") for (int n = 0; n < 2; ++n)                          \
            _Pragma("unroll") for (int kk = 0; kk < 2; ++kk)                   \
                acc[mq * 4 + i][nq * 2 + n] =                                  \
                    __builtin_amdgcn_mfma_f32_16x16x32_bf16(                   \
                        af[i][kk], bfr[n][kk], acc[mq * 4 + i][nq * 2 + n],    \
                        0, 0, 0);                                              \
    __builtin_amdgcn_s_setprio(0);                                             \
    __builtin_amdgcn_s_barrier();

    for (int t = 0; t < NT; ++t) {
        const int buf = t & 1;
        // ---- p1: (mq0, nq0) ----
        RD_A(0); RD_B(0);
        if (t + 1 < NT) stg(Ag + (size_t)128 * K + (t + 1) * 64, &shA[buf ^ 1][1][0]);
        MM(0, 0);
        // ---- p2: (mq1, nq0), B kept ----
        RD_A(1);
        if (t + 1 < NT) stg(Bg + (size_t)128 * K + (t + 1) * 64, &shB[buf ^ 1][1][0]);
        MM(1, 0);
        // ---- p3: (mq0, nq1) ----
        RD_A(0); RD_B(1);
        if (t + 2 < NT) stg(Bg + (t + 2) * 64, &shB[buf][0][0]);
        MM(0, 1);
        // ---- p4: (mq1, nq1), B kept ----
        RD_A(1);
        if (t + 2 < NT) stg(Ag + (t + 2) * 64, &shA[buf][0][0]);
        if (t + 2 >= NT) { VMCNT(0); } else { VMCNT(4); }
        MM(1, 1);
    }
#undef RD_A
#undef RD_B
#undef MM

    // epilogue: C/D map col=lane&15, row=(lane>>4)*4+reg; interleaved tiling
    const int cif = rl;
    const int rif = lg << 2;

    if constexpr (V == 1) {
        const float sc2 = scale * 1.4426950408889634f;
        const float sh2 = -8.656170245333781f;   // -6 * log2(e)
        float rs[8][4];
        #pragma unroll
        for (int m = 0; m < 8; ++m)
            #pragma unroll
            for (int r = 0; r < 4; ++r) rs[m][r] = 0.f;

        #pragma unroll
        for (int m = 0; m < 8; ++m) {
            const int grow = m0 + m * 32 + wr16 + rif;
            #pragma unroll
            for (int n = 0; n < 4; ++n) {
                const int col = n0 + n * 64 + wc16 + cif;
                #pragma unroll
                for (int r = 0; r < 4; ++r) {
                    const float e = exp2f(fmaf(acc[m][n][r], sc2, sh2));
                    rs[m][r] += e;
                    C[(size_t)(grow + r) * N + col] = (OutT)e;
                }
            }
        }
        #pragma unroll
        for (int m = 0; m < 8; ++m)
            #pragma unroll
            for (int r = 0; r < 4; ++r) {
                #pragma unroll
                for (int msk = 1; msk < 16; msk <<= 1)
                    rs[m][r] += __shfl_xor(rs[m][r], msk);
            }
        if (rl == 0) {
            const int slot = bx * 4 + wc;
            #pragma unroll
            for (int m = 0; m < 8; ++m) {
                const int grow = m0 + m * 32 + wr16 + rif;
                #pragma unroll
                for (int r = 0; r < 4; ++r)
                    pRow[(size_t)(grow + r) * 32 + slot] = rs[m][r];
            }
        }
    } else {  // V == 0: QKV routing
        #pragma unroll
        for (int m = 0; m < 8; ++m) {
            const int grow = m0 + m * 32 + wr16 + rif;
            #pragma unroll
            for (int n = 0; n < 4; ++n) {
                const int col = n0 + n * 64 + wc16 + cif;
                const float bb = bias[col];
                if (col < 1024) {
                    #pragma unroll
                    for (int r = 0; r < 4; ++r)
                        C[(size_t)(grow + r) * 1024 + col] = (OutT)(acc[m][n][r] + bb);
                } else if (col < 2048) {
                    #pragma unroll
                    for (int r = 0; r < 4; ++r)
                        C[NX + (size_t)(grow + r) * 1024 + (col - 1024)] = (OutT)(acc[m][n][r] + bb);
                } else {
                    const int batch = grow >> 11, s = grow & 2047, d = col - 2048;
                    bf16x4v pk;
                    #pragma unroll
                    for (int r = 0; r < 4; ++r) pk[r] = (bf16)(acc[m][n][r] + bb);
                    *(bf16x4v*)&vT[((size_t)batch << 21) + ((size_t)d << 11) + s] = pk;
                }
            }
        }
    }
}

// ---------------------------------------------------------------------------
// 2-phase 128x128 GEMM (round-5 proven) — PV only.
// out = (P~ V)/rowsum; inv[] reduced from pRow at block entry.
// ---------------------------------------------------------------------------
__global__ __launch_bounds__(256)
void gemm_pv(const bf16* __restrict__ A, const bf16* __restrict__ B,
             float* __restrict__ C, const float* __restrict__ pRow,
             int N, int K, long sAz, long sBz, long sCz)
{
    __shared__ bf16 lA[128 * 64];
    __shared__ bf16 lB[128 * 64];
    __shared__ float inv[128];
    const int z = blockIdx.z;
    A += (size_t)z * sAz;
    B += (size_t)z * sBz;
    C += (size_t)z * sCz;
    pRow += (size_t)z * (SB * 32);

    const int gx = gridDim.x;
    const int nwg = gx * gridDim.y;
    const int orig = (int)blockIdx.y * gx + (int)blockIdx.x;
    const int q8 = nwg >> 3;
    const int tile = (orig & 7) * q8 + (orig >> 3);
    const int bx = tile % gx;
    const int by = tile / gx;

    const int n0 = bx * 128;
    const int m0 = by * 128;
    const int t = threadIdx.x;
    const int lane = t & 63;
    const int wid = t >> 6;
    const int wr = wid >> 1, wc = wid & 1;

    if (t < 128) {
        const float4* pr = (const float4*)&pRow[(size_t)(m0 + t) * 32];
        float s = 0.f;
        #pragma unroll
        for (int j = 0; j < 8; ++j) {
            float4 f = pr[j];
            s += f.x + f.y + f.z + f.w;
        }
        inv[t] = 1.0f / s;
    }
    __syncthreads();

    f32x4 acc[4][4];
    #pragma unroll
    for (int m = 0; m < 4; ++m)
        #pragma unroll
        for (int n = 0; n < 4; ++n) acc[m][n] = (f32x4){0.f, 0.f, 0.f, 0.f};

    for (int k0 = 0; k0 < K; k0 += 64) {
        #pragma unroll
        for (int l = 0; l < 4; ++l) {
            const int idx = l * 256 + t;
            const int row = idx >> 3;
            const int c   = idx & 7;
            const int gc  = c ^ (row & 7);
            gload_lds16(A + (size_t)(m0 + row) * K + k0 + gc * 8, &lA[idx * 8]);
            gload_lds16(B + (size_t)(n0 + row) * K + k0 + gc * 8, &lB[idx * 8]);
        }
        __syncthreads();
        #pragma unroll
        for (int kk = 0; kk < 2; ++kk) {
            bf16x8v af[4], bfr[4];
            #pragma unroll
            for (int m = 0; m < 4; ++m) {
                const int row = wr * 64 + m * 16 + (lane & 15);
                const int ch  = (kk * 4 + (lane >> 4)) ^ (row & 7);
                af[m] = *(const bf16x8v*)&lA[row * 64 + ch * 8];
            }
            #pragma unroll
            for (int n = 0; n < 4; ++n) {
                const int row = wc * 64 + n * 16 + (lane & 15);
                const int ch  = (kk * 4 + (lane >> 4)) ^ (row & 7);
                bfr[n] = *(const bf16x8v*)&lB[row * 64 + ch * 8];
            }
            #pragma unroll
            for (int m = 0; m < 4; ++m)
                #pragma unroll
                for (int n = 0; n < 4; ++n)
                    acc[m][n] = __builtin_amdgcn_mfma_f32_16x16x32_bf16(
                        af[m], bfr[n], acc[m][n], 0, 0, 0);
        }
        __syncthreads();
    }

    const int cif = lane & 15;
    const int rif = (lane >> 4) << 2;
    #pragma unroll
    for (int m = 0; m < 4; ++m) {
        const int gm = m0 + wr * 64 + m * 16 + rif;
        const int rloc = wr * 64 + m * 16 + rif;
        #pragma unroll
        for (int n = 0; n < 4; ++n) {
            const int col = n0 + wc * 64 + n * 16 + cif;
            #pragma unroll
            for (int r = 0; r < 4; ++r)
                C[(size_t)(gm + r) * N + col] = acc[m][n][r] * inv[rloc + r];
        }
    }
}

// ---------------------------------------------------------------------------
extern "C" void kernel_launch(void* const* d_in, const int* in_sizes, int n_in,
                              void* d_out, int out_size, void* d_ws, size_t ws_size,
                              hipStream_t stream)
{
    const float* x1 = (const float*)d_in[0];
    const float* Wq = (const float*)d_in[1];
    const float* bq = (const float*)d_in[2];
    const float* Wk = (const float*)d_in[3];
    const float* bk = (const float*)d_in[4];
    const float* Wv = (const float*)d_in[5];
    const float* bv = (const float*)d_in[6];
    float* out = (float*)d_out;

    // workspace layout (bf16 elements unless noted)
    bf16* xb     = (bf16*)d_ws;             // x bf16; reused as pRow after QKV
    bf16* wb     = xb + NX;                 // 3*1048576 (Wq,Wk,Wv rows x 1024)
    bf16* qkb    = wb + 3 * NW;             // 2*8388608 (q then k)
    bf16* vTb    = qkb + 2 * (size_t)NX;    // 8388608 (V^T per batch [D][S])
    bf16* scores = vTb + NX;                // 4*2048*2048 (P~)
    float* biases = (float*)(scores + 4 * (size_t)SB * SB); // 3072 f32
    float* partial = (float*)xb;            // [4][2048][32] f32 (xb dead post-QKV)

    // 1. convert inputs to bf16
    convert_kernel<<<dim3(2048), dim3(256), 0, stream>>>(
        x1, Wq, Wk, Wv, bq, bk, bv, xb, wb, biases);

    // 2. fused QKV projection (8-phase 256^2): M=8192, N=3072, K=1024
    gemm8<0, bf16><<<dim3(384, 1, 1), dim3(512), 0, stream>>>(
        xb, wb, qkb, vTb, biases, nullptr, 1024, 1024, 12, 0L, 0L, 0L, 1.0f);

    // 3. P~ = exp(QK^T/32 - 6) + partials (8-phase 256^2): 256 blocks
    gemm8<1, bf16><<<dim3(64, 1, 4), dim3(512), 0, stream>>>(
        qkb, qkb + NX, scores, nullptr, nullptr, partial, SB, DD, 8,
        (long)(SB * DD), (long)(SB * DD), (long)(SB * SB), 1.0f / 32.0f);

    // 4. out = (P~ V)/rowsum (2-phase 128^2): M=2048, N=1024, K=2048
    gemm_pv<<<dim3(8, 16, 4), dim3(256), 0, stream>>>(
        scores, vTb, out, partial, DD, SB,
        (long)(SB * SB), (long)(SB * DD), (long)(SB * DD));
}

// Round 9
// 162.337 us; speedup vs baseline: 1.1131x; 1.0950x over previous
//
#include <hip/hip_runtime.h>
#include <cstdint>
#include <cstddef>

using bf16 = __bf16;
typedef float f32x4 __attribute__((ext_vector_type(4)));
typedef __bf16 bf16x8v __attribute__((ext_vector_type(8)));
typedef __bf16 bf16x4v __attribute__((ext_vector_type(4)));

// Problem constants: B=4, S=2048, D=1024
#define NX   8388608      // 4*2048*1024
#define NW   1048576      // 1024*1024
#define SB   2048
#define DD   1024

__device__ __forceinline__ void gload_lds16(const bf16* g, bf16* l) {
    __builtin_amdgcn_global_load_lds(
        (const __attribute__((address_space(1))) void*)(g),
        (__attribute__((address_space(3))) void*)(l), 16, 0, 0);
}

// ---------------------------------------------------------------------------
// Convert fp32 inputs -> bf16 in workspace; copy biases (fp32) contiguous.
// ---------------------------------------------------------------------------
__global__ __launch_bounds__(256)
void convert_kernel(const float* __restrict__ x1,
                    const float* __restrict__ Wq, const float* __restrict__ Wk,
                    const float* __restrict__ Wv,
                    const float* __restrict__ bq, const float* __restrict__ bk,
                    const float* __restrict__ bv,
                    bf16* __restrict__ xb, bf16* __restrict__ wb,
                    float* __restrict__ biases)
{
    const int NX4 = NX / 4;
    const int NW4 = NW / 4;
    const int NMAT = NX4 + 3 * NW4;
    const int total = NMAT + 768;
    for (int i = blockIdx.x * 256 + threadIdx.x; i < total; i += gridDim.x * 256) {
        if (i < NMAT) {
            const float* src; bf16* dst; int j;
            if (i < NX4) { src = x1; dst = xb; j = i; }
            else {
                int w = (i - NX4) / NW4;
                j = (i - NX4) - w * NW4;
                src = (w == 0) ? Wq : (w == 1) ? Wk : Wv;
                dst = wb + (size_t)w * NW;
            }
            float4 f = ((const float4*)src)[j];
            bf16x4v o;
            o[0] = (bf16)f.x; o[1] = (bf16)f.y; o[2] = (bf16)f.z; o[3] = (bf16)f.w;
            ((bf16x4v*)dst)[j] = o;
        } else {
            int j = i - NMAT;
            const float* src = (j < 256) ? bq : (j < 512) ? bk : bv;
            ((float4*)biases)[j] = ((const float4*)src)[j & 255];
        }
    }
}

// ---------------------------------------------------------------------------
// Double-buffered 2-phase 128x128 GEMM (catalog T3-minimum recipe applied to
// the proven m97-structure kernel). Per K-tile:
//   vmcnt(8) [counted: this tile's loads issued a full tile earlier]
//   -> barrier -> all 16 ds_read_b128 -> lgkmcnt(0)+sched_barrier(0)
//   -> barrier -> stage(t+2) into freed buffer [loads cross barriers]
//   -> 32 MFMA.  Tail: vmcnt(0) at t=NT-1.
// C[m][n] = scale * sum_k A[m][k]*B[n][k] (+ epilogue routing)
// A: M x K, B: N x K row-major bf16 (K-contiguous). 4 waves (2x2 of 64x64),
// mfma_f32_16x16x32_bf16. Conflict-free XOR swizzle (chunk ^= row&7) via
// pre-swizzled global source + swizzled ds_read (0 conflicts, rounds 1/3/5).
// T1 XCD-aware bijective block swizzle (nwg % 8 == 0).
// V=0: fused QKV epilogue (bias; col<1024 -> q, <2048 -> k, else v written
//      transposed [b][d][s]).
// V=1: scores: P~ = exp2(acc*scale*log2e - 6*log2e) bf16 + partial row-sums
//      pRow[row*32 + bx*2 + wc] (deterministic, no atomics).
// V=2: PV: f32 out scaled by 1/rowsum (reduced from pRow at block entry).
// ---------------------------------------------------------------------------
template<int V, typename OutT>
__global__ __launch_bounds__(256)
void gemm_bt(const bf16* __restrict__ A, const bf16* __restrict__ B,
             OutT* __restrict__ C, bf16* __restrict__ vT,
             const float* __restrict__ bias, float* __restrict__ pRow,
             int N, int K,
             long sAz, long sBz, long sCz, float scale)
{
    __shared__ bf16 lA[2][128 * 64];
    __shared__ bf16 lB[2][128 * 64];
    __shared__ float inv[128];   // V==2 only
    const int z = blockIdx.z;
    A += (size_t)z * sAz;
    B += (size_t)z * sBz;
    C += (size_t)z * sCz;
    if constexpr (V == 1 || V == 2) pRow += (size_t)z * (SB * 32);

    // T1: XCD-aware bijective swizzle of the flattened 2D grid
    const int gx = gridDim.x;
    const int nwg = gx * gridDim.y;
    const int orig = (int)blockIdx.y * gx + (int)blockIdx.x;
    const int q8 = nwg >> 3;
    const int tile = (orig & 7) * q8 + (orig >> 3);
    const int bx = tile % gx;
    const int by = tile / gx;

    const int n0 = bx * 128;
    const int m0 = by * 128;
    const int t = threadIdx.x;
    const int lane = t & 63;
    const int wid = t >> 6;
    const int wr = wid >> 1, wc = wid & 1;

    if constexpr (V == 2) {
        // reduce 32 partial row-sums per row -> inv[] in LDS
        if (t < 128) {
            const float4* pr = (const float4*)&pRow[(size_t)(m0 + t) * 32];
            float s = 0.f;
            #pragma unroll
            for (int j = 0; j < 8; ++j) {
                float4 f = pr[j];
                s += f.x + f.y + f.z + f.w;
            }
            inv[t] = 1.0f / s;
        }
        __syncthreads();
    }

    f32x4 acc[4][4];
    #pragma unroll
    for (int m = 0; m < 4; ++m)
        #pragma unroll
        for (int n = 0; n < 4; ++n) acc[m][n] = (f32x4){0.f, 0.f, 0.f, 0.f};

    // stage one full K-tile (A+B, 8 gload_lds per thread, FIFO order fixed)
    auto stage = [&](int b, int k0) {
        #pragma unroll
        for (int l = 0; l < 4; ++l) {
            const int idx = l * 256 + t;
            const int row = idx >> 3;
            const int c   = idx & 7;
            const int gc  = c ^ (row & 7);   // inverse-swizzled source chunk
            gload_lds16(A + (size_t)(m0 + row) * K + k0 + gc * 8, &lA[b][idx * 8]);
            gload_lds16(B + (size_t)(n0 + row) * K + k0 + gc * 8, &lB[b][idx * 8]);
        }
    };

    const int NT = K >> 6;

    // prologue: tiles 0 and 1 in flight (16 loads/thread outstanding)
    stage(0, 0);
    stage(1, 64);

    for (int tt = 0; tt < NT; ++tt) {
        const int cur = tt & 1;
        // counted wait: tile tt resident (its 8 loads are the oldest)
        if (tt == NT - 1) asm volatile("s_waitcnt vmcnt(0)" ::: "memory");
        else              asm volatile("s_waitcnt vmcnt(8)" ::: "memory");
        __builtin_amdgcn_s_barrier();

        // read ALL fragments for both kk halves
        bf16x8v af[2][4], bfr[2][4];
        #pragma unroll
        for (int kk = 0; kk < 2; ++kk) {
            #pragma unroll
            for (int m = 0; m < 4; ++m) {
                const int row = wr * 64 + m * 16 + (lane & 15);
                const int ch  = (kk * 4 + (lane >> 4)) ^ (row & 7);
                af[kk][m] = *(const bf16x8v*)&lA[cur][row * 64 + ch * 8];
            }
            #pragma unroll
            for (int n = 0; n < 4; ++n) {
                const int row = wc * 64 + n * 16 + (lane & 15);
                const int ch  = (kk * 4 + (lane >> 4)) ^ (row & 7);
                bfr[kk][n] = *(const bf16x8v*)&lB[cur][row * 64 + ch * 8];
            }
        }
        asm volatile("s_waitcnt lgkmcnt(0)" ::: "memory");
        __builtin_amdgcn_sched_barrier(0);
        __builtin_amdgcn_s_barrier();   // all waves' reads of buf[cur] retired

        // refill the just-freed buffer; loads stay in flight across barriers
        if (tt + 2 < NT) stage(cur, (tt + 2) * 64);

        #pragma unroll
        for (int kk = 0; kk < 2; ++kk)
            #pragma unroll
            for (int m = 0; m < 4; ++m)
                #pragma unroll
                for (int n = 0; n < 4; ++n)
                    acc[m][n] = __builtin_amdgcn_mfma_f32_16x16x32_bf16(
                        af[kk][m], bfr[kk][n], acc[m][n], 0, 0, 0);
    }

    // epilogue: C/D map col=lane&15, row=(lane>>4)*4+reg (m89-verified)
    const int cif = lane & 15;
    const int rif = (lane >> 4) << 2;

    if constexpr (V == 1) {
        const float sc2 = scale * 1.4426950408889634f;
        const float sh2 = -8.656170245333781f;   // -6 * log2(e)
        float rs[4][4];   // [m][r] partial row sums over this lane's cols
        #pragma unroll
        for (int m = 0; m < 4; ++m)
            #pragma unroll
            for (int r = 0; r < 4; ++r) rs[m][r] = 0.f;

        #pragma unroll
        for (int m = 0; m < 4; ++m) {
            const int gm = m0 + wr * 64 + m * 16 + rif;
            #pragma unroll
            for (int n = 0; n < 4; ++n) {
                const int col = n0 + wc * 64 + n * 16 + cif;
                #pragma unroll
                for (int r = 0; r < 4; ++r) {
                    const float e = exp2f(fmaf(acc[m][n][r], sc2, sh2));
                    rs[m][r] += e;
                    C[(size_t)(gm + r) * N + col] = (OutT)e;
                }
            }
        }
        // reduce over the 16 rl-lanes (same rows, different cols)
        #pragma unroll
        for (int m = 0; m < 4; ++m)
            #pragma unroll
            for (int r = 0; r < 4; ++r) {
                #pragma unroll
                for (int msk = 1; msk < 16; msk <<= 1)
                    rs[m][r] += __shfl_xor(rs[m][r], msk);
            }
        if ((lane & 15) == 0) {
            const int slot = bx * 2 + wc;
            #pragma unroll
            for (int m = 0; m < 4; ++m) {
                const int gm = m0 + wr * 64 + m * 16 + rif;
                #pragma unroll
                for (int r = 0; r < 4; ++r)
                    pRow[(size_t)(gm + r) * 32 + slot] = rs[m][r];
            }
        }
    } else {
        #pragma unroll
        for (int m = 0; m < 4; ++m) {
            const int gm = m0 + wr * 64 + m * 16 + rif;
            #pragma unroll
            for (int n = 0; n < 4; ++n) {
                const int col = n0 + wc * 64 + n * 16 + cif;
                if constexpr (V == 0) {
                    const float bb = bias[col];
                    if (col < 1024) {
                        #pragma unroll
                        for (int r = 0; r < 4; ++r)
                            C[(size_t)(gm + r) * 1024 + col] = (OutT)(acc[m][n][r] + bb);
                    } else if (col < 2048) {
                        #pragma unroll
                        for (int r = 0; r < 4; ++r)
                            C[NX + (size_t)(gm + r) * 1024 + (col - 1024)] = (OutT)(acc[m][n][r] + bb);
                    } else {
                        const int batch = gm >> 11, s = gm & 2047, d = col - 2048;
                        bf16x4v pk;
                        #pragma unroll
                        for (int r = 0; r < 4; ++r) pk[r] = (bf16)(acc[m][n][r] + bb);
                        *(bf16x4v*)&vT[((size_t)batch << 21) + ((size_t)d << 11) + s] = pk;
                    }
                } else {  // V == 2: normalize by row sum
                    const int rloc = wr * 64 + m * 16 + rif;
                    #pragma unroll
                    for (int r = 0; r < 4; ++r)
                        C[(size_t)(gm + r) * N + col] = (OutT)(acc[m][n][r] * inv[rloc + r]);
                }
            }
        }
    }
}

// ---------------------------------------------------------------------------
extern "C" void kernel_launch(void* const* d_in, const int* in_sizes, int n_in,
                              void* d_out, int out_size, void* d_ws, size_t ws_size,
                              hipStream_t stream)
{
    const float* x1 = (const float*)d_in[0];
    const float* Wq = (const float*)d_in[1];
    const float* bq = (const float*)d_in[2];
    const float* Wk = (const float*)d_in[3];
    const float* bk = (const float*)d_in[4];
    const float* Wv = (const float*)d_in[5];
    const float* bv = (const float*)d_in[6];
    float* out = (float*)d_out;

    // workspace layout (bf16 elements unless noted)
    bf16* xb     = (bf16*)d_ws;             // x bf16; reused as pRow after QKV
    bf16* wb     = xb + NX;                 // 3*1048576 (Wq,Wk,Wv rows x 1024)
    bf16* qkb    = wb + 3 * NW;             // 2*8388608 (q then k)
    bf16* vTb    = qkb + 2 * (size_t)NX;    // 8388608 (V^T per batch [D][S])
    bf16* scores = vTb + NX;                // 4*2048*2048 (P~)
    float* biases = (float*)(scores + 4 * (size_t)SB * SB); // 3072 f32
    float* partial = (float*)xb;            // [4][2048][32] f32 (xb dead post-QKV)

    // 1. convert inputs to bf16
    convert_kernel<<<dim3(2048), dim3(256), 0, stream>>>(
        x1, Wq, Wk, Wv, bq, bk, bv, xb, wb, biases);

    // 2. fused QKV projection: M=8192, N=3072 (q|k|vT), K=1024
    gemm_bt<0, bf16><<<dim3(24, 64, 1), dim3(256), 0, stream>>>(
        xb, wb, qkb, vTb, biases, nullptr, 1024, 1024, 0L, 0L, 0L, 1.0f);

    // 3. P~ = exp(QK^T/32 - 6) per batch + partial row sums: M=N=2048, K=1024
    gemm_bt<1, bf16><<<dim3(16, 16, 4), dim3(256), 0, stream>>>(
        qkb, qkb + NX, scores, nullptr, nullptr, partial, SB, DD,
        (long)(SB * DD), (long)(SB * DD), (long)(SB * SB), 1.0f / 32.0f);

    // 4. out = (P~ V) / rowsum per batch: M=2048, N=1024, K=2048, f32 out
    gemm_bt<2, float><<<dim3(8, 16, 4), dim3(256), 0, stream>>>(
        scores, vTb, out, nullptr, nullptr, partial, DD, SB,
        (long)(SB * SB), (long)(SB * DD), (long)(SB * DD), 1.0f);
}